// Round 6
// baseline (172.394 us; speedup 1.0000x reference)
//
#include <hip/hip_runtime.h>
#include <math.h>

#define NB 4
#define SL 1024
#define EMB 1024
#define NH 16
#define HD 64
#define QB 128

typedef __attribute__((ext_vector_type(8))) short bf16x8;
typedef __attribute__((ext_vector_type(4))) float f32x4;

// round-half-up f32->bf16 pack (inputs finite)
static __device__ __forceinline__ unsigned pk2(float a, float b) {
    unsigned x = __float_as_uint(a) + 0x8000u;
    unsigned y = __float_as_uint(b) + 0x8000u;
    return (x >> 16) | (y & 0xFFFF0000u);
}
static __device__ __forceinline__ float exp2_fast(float x) {
    float r; asm("v_exp_f32 %0, %1" : "=v"(r) : "v"(x)); return r;
}
static __device__ __forceinline__ void gload_lds16(const void* g, void* l) {
    __builtin_amdgcn_global_load_lds(
        (const __attribute__((address_space(1))) unsigned int*)g,
        (__attribute__((address_space(3))) unsigned int*)l, 16, 0, 0);
}

// ---------------- Fused prep ----------------
// [0,512):      Wb = bf16(W)
// [512,2560):   Kb[b,h,k,d] = bf16(K[b,k,h,d])
// [2560,4608):  Qb[b,h,q,d] = bf16(Q[b,q,h,d])
// [4608,5120):  Vt[b,h,d,k] = bf16(V^T)      (transpose via LDS)
// [5120,9216):  Mbt[(b*16+c)*SL+q] bitmask
__global__ __launch_bounds__(256) void prep(
    const float* __restrict__ W, unsigned short* __restrict__ Wb,
    const float* __restrict__ Kf, unsigned short* __restrict__ Kb,
    const float* __restrict__ Qf, unsigned short* __restrict__ Qb,
    const float* __restrict__ V, unsigned short* __restrict__ Vt,
    const int* __restrict__ mask, unsigned long long* __restrict__ Mbt)
{
    __shared__ unsigned short sT[128 * 68];
    const int bid = blockIdx.x, tid = threadIdx.x;

    if (bid < 512) {
        int i = (bid * 256 + tid) * 8;
        float4 f0 = *(const float4*)&W[i];
        float4 f1 = *(const float4*)&W[i + 4];
        uint4 u = { pk2(f0.x,f0.y), pk2(f0.z,f0.w), pk2(f1.x,f1.y), pk2(f1.z,f1.w) };
        *(uint4*)&Wb[i] = u;
    } else if (bid < 4608) {
        int t = bid - 512;
        const float* src = Kf;
        unsigned short* dst = Kb;
        if (t >= 2048) { t -= 2048; src = Qf; dst = Qb; }
        int b = t >> 9, h = (t >> 5) & 15, k0 = (t & 31) * 32;
        int r = tid >> 3, d = (tid & 7) * 8;
        const float* gp = &src[((size_t)(b * SL + k0 + r)) * EMB + h * HD + d];
        float4 f0 = *(const float4*)gp, f1 = *(const float4*)(gp + 4);
        uint4 u = { pk2(f0.x,f0.y), pk2(f0.z,f0.w), pk2(f1.x,f1.y), pk2(f1.z,f1.w) };
        *(uint4*)&dst[((size_t)((b * NH + h) * SL + k0 + r)) * HD + d] = u;
    } else if (bid < 5120) {
        int t = bid - 4608;
        int bh = t >> 3, kb = t & 7;
        int b = bh >> 4, h = bh & 15;
        int k0 = kb * 128;
        #pragma unroll
        for (int i = 0; i < 4; ++i) {
            int lin = (i * 256 + tid) * 8;
            int r = lin >> 6, d = lin & 63;
            const float* gp = &V[((size_t)(b * SL + k0 + r)) * EMB + h * HD + d];
            float4 f0 = *(const float4*)gp, f1 = *(const float4*)(gp + 4);
            uint2 u0 = { pk2(f0.x,f0.y), pk2(f0.z,f0.w) };
            uint2 u1 = { pk2(f1.x,f1.y), pk2(f1.z,f1.w) };
            *(uint2*)&sT[r * 68 + d]     = u0;
            *(uint2*)&sT[r * 68 + d + 4] = u1;
        }
        __syncthreads();
        #pragma unroll
        for (int p = 0; p < 4; ++p) {
            int d = p * 16 + (tid >> 4);
            int c = tid & 15;
            unsigned v[4];
            #pragma unroll
            for (int j = 0; j < 4; ++j) {
                unsigned lo = sT[(c * 8 + 2 * j) * 68 + d];
                unsigned hi = sT[(c * 8 + 2 * j + 1) * 68 + d];
                v[j] = lo | (hi << 16);
            }
            uint4 u = { v[0], v[1], v[2], v[3] };
            *(uint4*)&Vt[((size_t)(bh * HD + d)) * SL + k0 + c * 8] = u;
        }
    } else {
        int t = bid - 5120;
        int lane = tid & 63;
        #pragma unroll
        for (int r = 0; r < 4; ++r) {
            int wid = (t * 4 + (tid >> 6)) * 4 + r;
            int c = wid & 15, q = (wid >> 4) & 1023, bb = wid >> 14;
            int mv = mask[((size_t)bb * SL + q) * SL + c * 64 + lane];
            unsigned long long bits = __ballot(mv != 0);
            if (lane == 0) Mbt[((size_t)bb * 16 + c) * SL + q] = bits;
        }
    }
}

// ---------------- Flash attention v6 ----------------
// S^T = K Q^T, O^T = V^T P. Q/K/V all pre-converted bf16, staged via gload_lds16
// (zero staging VALU). XCD-swizzled 1D grid: all 8 q-blocks of a (b,h) land on one
// XCD -> K/V stay L2-resident across the 8 blocks. sQ unioned with sP (Q staging is
// prologue-only). Fixed-shift softmax; l via ones-MFMA; mask via VALU cndmask words.
__global__ __launch_bounds__(256, 2) void attn_mfma(
    const unsigned short* __restrict__ Qb, const unsigned short* __restrict__ Kb,
    const unsigned short* __restrict__ Vt,
    const unsigned long long* __restrict__ Mbt,
    unsigned short* __restrict__ Oa)
{
    // XCD swizzle: bid&7 selects head-group; 8 q-blocks of each (b,h) share an XCD
    const int bid = blockIdx.x;
    const int bh  = ((bid >> 6) << 3) | (bid & 7);   // [0,64)
    const int q0  = ((bid >> 3) & 7) * QB;
    const int b = bh >> 4, h = bh & 15;

    const int tid = threadIdx.x;
    const int w = tid >> 6, lane = tid & 63;
    const int m16 = lane & 15, quad = lane >> 4;
    const int lr = lane >> 3, lc = lane & 7;

    __shared__ __align__(16) unsigned short sQP[QB * 72];     // Q (stride 64) then P (stride 72)
    __shared__ __align__(16) unsigned short sK[2][64 * 64];
    __shared__ __align__(16) unsigned short sVt[2][64 * 64];

    const size_t vbase = (size_t)((b * NH + h) * HD) * SL;   // Vt row d, len SL
    const size_t kbase = (size_t)((b * NH + h) * SL) * HD;   // Kb/Qb row k, len 64

    // tile0 K/V + Q staging, all DMA (swizzled source chunks)
    #pragma unroll
    for (int i = 0; i < 2; ++i) {
        int row = w * 16 + i * 8;
        gload_lds16(&Vt[vbase + (size_t)(row + lr) * SL + (lc ^ lr) * 8], &sVt[0][row * 64]);
        gload_lds16(&Kb[kbase + (size_t)(row + lr) * HD + (lc ^ lr) * 8], &sK[0][row * 64]);
    }
    #pragma unroll
    for (int i = 0; i < 4; ++i) {
        int row = w * 32 + i * 8;
        gload_lds16(&Qb[kbase + (size_t)(q0 + row + lr) * HD + (lc ^ lr) * 8], &sQP[row * 64]);
    }
    __syncthreads();   // all DMA landed

    // hoist Q B-frags (reads own wave's rows only)
    bf16x8 bQ[2][2];
    #pragma unroll
    for (int u = 0; u < 2; ++u) {
        int qrow = w * 32 + u * 16 + m16;
        #pragma unroll
        for (int hh = 0; hh < 2; ++hh)
            bQ[u][hh] = *(const bf16x8*)&sQP[qrow * 64 + (((hh * 4 + quad) ^ (qrow & 7)) * 8)];
    }
    __syncthreads();   // Q region is dead; sQP becomes P (strides overlap across waves)

    f32x4 O[2][4] = {};
    f32x4 lacc[2] = {};
    const float CSC = 0.125f * 1.44269504f;
    const short one_bf = (short)0x3F80;
    const bf16x8 ones = { one_bf, one_bf, one_bf, one_bf, one_bf, one_bf, one_bf, one_bf };

    for (int kt = 0; kt < 16; ++kt) {
        const int bf = kt & 1;
        if (kt < 15) {
            const int k0n = (kt + 1) * 64;
            #pragma unroll
            for (int i = 0; i < 2; ++i) {
                int row = w * 16 + i * 8;
                gload_lds16(&Vt[vbase + (size_t)(row + lr) * SL + k0n + (lc ^ lr) * 8],
                            &sVt[bf ^ 1][row * 64]);
                gload_lds16(&Kb[kbase + (size_t)(k0n + row + lr) * HD + (lc ^ lr) * 8],
                            &sK[bf ^ 1][row * 64]);
            }
        }
        unsigned long long mb0 = Mbt[(size_t)(b * 16 + kt) * SL + q0 + w * 32 + m16];
        unsigned long long mb1 = Mbt[(size_t)(b * 16 + kt) * SL + q0 + w * 32 + 16 + m16];

        // scores: S^T[64k][32q]
        f32x4 sc[2][4];
        #pragma unroll
        for (int t = 0; t < 4; ++t) {
            int krow = t * 16 + m16;
            bf16x8 a0 = *(const bf16x8*)&sK[bf][krow * 64 + ((quad ^ (krow & 7)) * 8)];
            bf16x8 a1 = *(const bf16x8*)&sK[bf][krow * 64 + (((4 + quad) ^ (krow & 7)) * 8)];
            f32x4 z = {0.f, 0.f, 0.f, 0.f};
            sc[0][t] = __builtin_amdgcn_mfma_f32_16x16x32_bf16(a0, bQ[0][0], z,        0,0,0);
            sc[0][t] = __builtin_amdgcn_mfma_f32_16x16x32_bf16(a1, bQ[0][1], sc[0][t], 0,0,0);
            sc[1][t] = __builtin_amdgcn_mfma_f32_16x16x32_bf16(a0, bQ[1][0], z,        0,0,0);
            sc[1][t] = __builtin_amdgcn_mfma_f32_16x16x32_bf16(a1, bQ[1][1], sc[1][t], 0,0,0);
        }

        // exp2 (fixed shift) + VALU mask words on packed bf16, write P[q][k]
        #pragma unroll
        for (int u = 0; u < 2; ++u) {
            unsigned long long mb = u ? mb1 : mb0;
            unsigned wlo = (unsigned)mb, whi = (unsigned)(mb >> 32);
            unsigned short* pr = &sQP[(w * 32 + u * 16 + m16) * 72];
            #pragma unroll
            for (int t = 0; t < 4; ++t) {
                unsigned word = (t < 2) ? wlo : whi;
                unsigned nib = (word >> ((t & 1) * 16 + quad * 4)) & 0xFu;
                unsigned am0 = ((nib & 1u) ? 0xFFFFu : 0u) | ((nib & 2u) ? 0xFFFF0000u : 0u);
                unsigned am1 = ((nib & 4u) ? 0xFFFFu : 0u) | ((nib & 8u) ? 0xFFFF0000u : 0u);
                uint2 pw;
                pw.x = pk2(exp2_fast(sc[u][t][0] * CSC), exp2_fast(sc[u][t][1] * CSC)) & am0;
                pw.y = pk2(exp2_fast(sc[u][t][2] * CSC), exp2_fast(sc[u][t][3] * CSC)) & am1;
                *(uint2*)&pr[t * 16 + quad * 4] = pw;
            }
        }
        asm volatile("s_waitcnt lgkmcnt(0)" ::: "memory");   // wave-local P write->read

        bf16x8 bP[2][2];
        #pragma unroll
        for (int u = 0; u < 2; ++u)
            #pragma unroll
            for (int hh = 0; hh < 2; ++hh)
                bP[u][hh] = *(const bf16x8*)&sQP[(w * 32 + u * 16 + m16) * 72 + hh * 32 + quad * 8];

        // l accumulation: lacc += 1^T P
        lacc[0] = __builtin_amdgcn_mfma_f32_16x16x32_bf16(ones, bP[0][0], lacc[0], 0,0,0);
        lacc[0] = __builtin_amdgcn_mfma_f32_16x16x32_bf16(ones, bP[0][1], lacc[0], 0,0,0);
        lacc[1] = __builtin_amdgcn_mfma_f32_16x16x32_bf16(ones, bP[1][0], lacc[1], 0,0,0);
        lacc[1] = __builtin_amdgcn_mfma_f32_16x16x32_bf16(ones, bP[1][1], lacc[1], 0,0,0);

        // PV: O^T[64d][32q] += V^T P
        #pragma unroll
        for (int dt = 0; dt < 4; ++dt) {
            int drow = dt * 16 + m16;
            bf16x8 v0 = *(const bf16x8*)&sVt[bf][drow * 64 + ((quad ^ (drow & 7)) * 8)];
            bf16x8 v1 = *(const bf16x8*)&sVt[bf][drow * 64 + (((4 + quad) ^ (drow & 7)) * 8)];
            O[0][dt] = __builtin_amdgcn_mfma_f32_16x16x32_bf16(v0, bP[0][0], O[0][dt], 0,0,0);
            O[0][dt] = __builtin_amdgcn_mfma_f32_16x16x32_bf16(v1, bP[0][1], O[0][dt], 0,0,0);
            O[1][dt] = __builtin_amdgcn_mfma_f32_16x16x32_bf16(v0, bP[1][0], O[1][dt], 0,0,0);
            O[1][dt] = __builtin_amdgcn_mfma_f32_16x16x32_bf16(v1, bP[1][1], O[1][dt], 0,0,0);
        }

        __syncthreads();   // drains gloads into buf^1 + all waves done with buf
    }

    // epilogue: per-lane l (col q = m16), normalize, store bf16
    #pragma unroll
    for (int u = 0; u < 2; ++u) {
        float inv = 1.f / lacc[u][0];
        size_t base = ((size_t)(b * SL + q0 + w * 32 + u * 16 + m16)) * EMB + h * HD + quad * 4;
        #pragma unroll
        for (int dt = 0; dt < 4; ++dt) {
            uint2 ow = { pk2(O[u][dt][0] * inv, O[u][dt][1] * inv),
                         pk2(O[u][dt][2] * inv, O[u][dt][3] * inv) };
            *(uint2*)&Oa[base + dt * 16] = ow;
        }
    }
}

// ---------------- Projection: C[4096][1024] = A_bf16 @ W_bf16^T + bias ----------------
// 512 threads (8 waves), 128x128 tile, wave = 64m x 32n, BK=64, dbuf, 1 barrier/it.
__global__ __launch_bounds__(512, 2) void proj_mfma(
    const unsigned short* __restrict__ A, const unsigned short* __restrict__ Wb,
    const float* __restrict__ bias, float* __restrict__ C)
{
    const int n0 = blockIdx.x * 128;
    const int m0 = blockIdx.y * 128;
    const int tid = threadIdx.x;
    const int w = tid >> 6, lane = tid & 63;
    const int m16 = lane & 15, quad = lane >> 4;
    const int lr = lane >> 3, lc = lane & 7;
    const int wm = (w >> 2) * 64, wn = (w & 3) * 32;

    __shared__ __align__(16) unsigned short sA[2][128 * 64];
    __shared__ __align__(16) unsigned short sW[2][128 * 64];

    f32x4 acc[4][2] = {};

    #pragma unroll
    for (int i = 0; i < 2; ++i) {
        int r = w * 16 + i * 8;
        gload_lds16(&A [(size_t)(m0 + r + lr) * EMB + (lc ^ lr) * 8], &sA[0][r * 64]);
        gload_lds16(&Wb[(size_t)(n0 + r + lr) * EMB + (lc ^ lr) * 8], &sW[0][r * 64]);
    }
    __syncthreads();

    for (int it = 0; it < 16; ++it) {
        const int bf = it & 1;
        if (it < 15) {
            int e0 = (it + 1) * 64;
            #pragma unroll
            for (int i = 0; i < 2; ++i) {
                int r = w * 16 + i * 8;
                gload_lds16(&A [(size_t)(m0 + r + lr) * EMB + e0 + (lc ^ lr) * 8], &sA[bf ^ 1][r * 64]);
                gload_lds16(&Wb[(size_t)(n0 + r + lr) * EMB + e0 + (lc ^ lr) * 8], &sW[bf ^ 1][r * 64]);
            }
        }
        #pragma unroll
        for (int hh = 0; hh < 2; ++hh) {
            bf16x8 af[4], bw[2];
            #pragma unroll
            for (int mt = 0; mt < 4; ++mt) {
                int r = wm + mt * 16 + m16;
                af[mt] = *(const bf16x8*)&sA[bf][r * 64 + (((hh * 4 + quad) ^ (r & 7)) * 8)];
            }
            #pragma unroll
            for (int nt = 0; nt < 2; ++nt) {
                int r = wn + nt * 16 + m16;
                bw[nt] = *(const bf16x8*)&sW[bf][r * 64 + (((hh * 4 + quad) ^ (r & 7)) * 8)];
            }
            #pragma unroll
            for (int mt = 0; mt < 4; ++mt)
                #pragma unroll
                for (int nt = 0; nt < 2; ++nt)
                    acc[mt][nt] = __builtin_amdgcn_mfma_f32_16x16x32_bf16(af[mt], bw[nt], acc[mt][nt], 0,0,0);
        }
        __syncthreads();
    }

    #pragma unroll
    for (int nt = 0; nt < 2; ++nt) {
        float bv = bias[n0 + wn + nt * 16 + m16];
        #pragma unroll
        for (int mt = 0; mt < 4; ++mt) {
            size_t row = (size_t)(m0 + wm + mt * 16 + quad * 4);
            #pragma unroll
            for (int rg = 0; rg < 4; ++rg)
                C[(row + rg) * EMB + n0 + wn + nt * 16 + m16] = acc[mt][nt][rg] + bv;
        }
    }
}

extern "C" void kernel_launch(void* const* d_in, const int* in_sizes, int n_in,
                              void* d_out, int out_size, void* d_ws, size_t ws_size,
                              hipStream_t stream) {
    const float* Q    = (const float*)d_in[0];
    const float* K    = (const float*)d_in[1];
    const float* V    = (const float*)d_in[2];
    const int*   mask = (const int*)  d_in[3];
    const float* W    = (const float*)d_in[4];
    const float* bias = (const float*)d_in[5];

    unsigned short* Oa = (unsigned short*)d_ws;                              // 8.39 MB
    unsigned short* Wb = Oa + (size_t)NB * SL * EMB;                         // 2.10 MB
    unsigned long long* Mbt = (unsigned long long*)(Wb + (size_t)EMB * EMB); // 0.52 MB
    unsigned short* Vt = (unsigned short*)(Mbt + (size_t)NB * 16 * SL);      // 8.39 MB
    unsigned short* Kb = Vt + (size_t)NB * NH * HD * SL;                     // 8.39 MB
    unsigned short* Qbuf = Kb + (size_t)NB * NH * SL * HD;                   // 8.39 MB

    prep<<<9216, 256, 0, stream>>>(W, Wb, K, Kb, Q, Qbuf, V, Vt, mask, Mbt);
    attn_mfma<<<512, 256, 0, stream>>>(Qbuf, Kb, Vt, Mbt, Oa);
    proj_mfma<<<dim3(EMB / 128, (NB * SL) / 128), 512, 0, stream>>>(Oa, Wb, bias, (float*)d_out);
}

// Round 7
// 167.517 us; speedup vs baseline: 1.0291x; 1.0291x over previous
//
#include <hip/hip_runtime.h>
#include <math.h>

#define NB 4
#define SL 1024
#define EMB 1024
#define NH 16
#define HD 64
#define QB 64

typedef __attribute__((ext_vector_type(8))) short bf16x8;
typedef __attribute__((ext_vector_type(4))) float f32x4;

// round-half-up f32->bf16 pack (inputs finite)
static __device__ __forceinline__ unsigned pk2(float a, float b) {
    unsigned x = __float_as_uint(a) + 0x8000u;
    unsigned y = __float_as_uint(b) + 0x8000u;
    return (x >> 16) | (y & 0xFFFF0000u);
}
static __device__ __forceinline__ float exp2_fast(float x) {
    float r; asm("v_exp_f32 %0, %1" : "=v"(r) : "v"(x)); return r;
}
static __device__ __forceinline__ void gload_lds16(const void* g, void* l) {
    __builtin_amdgcn_global_load_lds(
        (const __attribute__((address_space(1))) unsigned int*)g,
        (__attribute__((address_space(3))) unsigned int*)l, 16, 0, 0);
}

// ---------------- Fused prep ----------------
// [0,512):     Wb = bf16(W)
// [512,2560):  Kb[b,h,k,d] = bf16(K[b,k,h,d])
// [2560,3072): Vt[b,h,d,k] = bf16(V^T)   (transpose via LDS)
// [3072,7168): Mbt[(b*16+c)*SL+q] bitmask
__global__ __launch_bounds__(256) void prep(
    const float* __restrict__ W, unsigned short* __restrict__ Wb,
    const float* __restrict__ Kf, unsigned short* __restrict__ Kb,
    const float* __restrict__ V, unsigned short* __restrict__ Vt,
    const int* __restrict__ mask, unsigned long long* __restrict__ Mbt)
{
    __shared__ unsigned short sT[128 * 68];
    const int bid = blockIdx.x, tid = threadIdx.x;

    if (bid < 512) {
        int i = (bid * 256 + tid) * 8;
        float4 f0 = *(const float4*)&W[i];
        float4 f1 = *(const float4*)&W[i + 4];
        uint4 u = { pk2(f0.x,f0.y), pk2(f0.z,f0.w), pk2(f1.x,f1.y), pk2(f1.z,f1.w) };
        *(uint4*)&Wb[i] = u;
    } else if (bid < 2560) {
        int t = bid - 512;
        int b = t >> 9, h = (t >> 5) & 15, k0 = (t & 31) * 32;
        int r = tid >> 3, d = (tid & 7) * 8;
        const float* gp = &Kf[((size_t)(b * SL + k0 + r)) * EMB + h * HD + d];
        float4 f0 = *(const float4*)gp, f1 = *(const float4*)(gp + 4);
        uint4 u = { pk2(f0.x,f0.y), pk2(f0.z,f0.w), pk2(f1.x,f1.y), pk2(f1.z,f1.w) };
        *(uint4*)&Kb[((size_t)((b * NH + h) * SL + k0 + r)) * HD + d] = u;
    } else if (bid < 3072) {
        int t = bid - 2560;
        int bh = t >> 3, kb = t & 7;
        int b = bh >> 4, h = bh & 15;
        int k0 = kb * 128;
        #pragma unroll
        for (int i = 0; i < 4; ++i) {
            int lin = (i * 256 + tid) * 8;
            int r = lin >> 6, d = lin & 63;
            const float* gp = &V[((size_t)(b * SL + k0 + r)) * EMB + h * HD + d];
            float4 f0 = *(const float4*)gp, f1 = *(const float4*)(gp + 4);
            uint2 u0 = { pk2(f0.x,f0.y), pk2(f0.z,f0.w) };
            uint2 u1 = { pk2(f1.x,f1.y), pk2(f1.z,f1.w) };
            *(uint2*)&sT[r * 68 + d]     = u0;
            *(uint2*)&sT[r * 68 + d + 4] = u1;
        }
        __syncthreads();
        #pragma unroll
        for (int p = 0; p < 4; ++p) {
            int d = p * 16 + (tid >> 4);
            int c = tid & 15;
            unsigned v[4];
            #pragma unroll
            for (int j = 0; j < 4; ++j) {
                unsigned lo = sT[(c * 8 + 2 * j) * 68 + d];
                unsigned hi = sT[(c * 8 + 2 * j + 1) * 68 + d];
                v[j] = lo | (hi << 16);
            }
            uint4 u = { v[0], v[1], v[2], v[3] };
            *(uint4*)&Vt[((size_t)(bh * HD + d)) * SL + k0 + c * 8] = u;
        }
    } else {
        int t = bid - 3072;
        int lane = tid & 63;
        #pragma unroll
        for (int r = 0; r < 4; ++r) {
            int wid = (t * 4 + (tid >> 6)) * 4 + r;
            int c = wid & 15, q = (wid >> 4) & 1023, bb = wid >> 14;
            int mv = mask[((size_t)bb * SL + q) * SL + c * 64 + lane];
            unsigned long long bits = __ballot(mv != 0);
            if (lane == 0) Mbt[((size_t)bb * 16 + c) * SL + q] = bits;
        }
    }
}

// ---------------- Flash attention v7 ----------------
// QB=64 (1024 blocks, 4/CU): wave w owns 16 q rows. LDS exactly 40960B.
// S^T = K Q^T, O^T = V^T P. K/V bf16 staged via gload_lds16 dbuf; Q read fp32 in
// prologue (once); sQ unioned with sP (both stride-64 XOR-chunk layout).
// Fixed-shift softmax; l via ones-MFMA; mask via VALU AND-words on packed bf16.
__global__ __launch_bounds__(256, 4) void attn_mfma(
    const float* __restrict__ Qf, const unsigned short* __restrict__ Kb,
    const unsigned short* __restrict__ Vt,
    const unsigned long long* __restrict__ Mbt,
    unsigned short* __restrict__ Oa)
{
    // XCD swizzle: bid&7 = XCD; all 16 q-blocks of a (b,h) share an XCD
    const int bid = blockIdx.x;
    const int bh  = ((bid >> 7) << 3) | (bid & 7);       // [0,64)
    const int q0  = ((bid >> 3) & 15) * QB;
    const int b = bh >> 4, h = bh & 15;

    const int tid = threadIdx.x;
    const int w = tid >> 6, lane = tid & 63;
    const int m16 = lane & 15, quad = lane >> 4;
    const int lr = lane >> 3, lc = lane & 7;
    const int sr0 = tid >> 3;

    __shared__ __align__(16) unsigned short sQP[QB * 64];    // Q then P, XOR-chunk swizzled
    __shared__ __align__(16) unsigned short sK [2][64 * 64];
    __shared__ __align__(16) unsigned short sVt[2][64 * 64];

    const size_t vbase = (size_t)((b * NH + h) * HD) * SL;   // Vt row d, len SL
    const size_t kbase = (size_t)((b * NH + h) * SL) * HD;   // Kb row k, len 64

    // tile0 K/V DMA
    #pragma unroll
    for (int i = 0; i < 2; ++i) {
        int row = w * 16 + i * 8;
        gload_lds16(&Vt[vbase + (size_t)(row + lr) * SL + (lc ^ lr) * 8], &sVt[0][row * 64]);
        gload_lds16(&Kb[kbase + (size_t)(row + lr) * HD + (lc ^ lr) * 8], &sK[0][row * 64]);
    }
    // stage Q fp32->bf16 (prologue only, 16 elems/thread)
    #pragma unroll
    for (int it = 0; it < 2; ++it) {
        int r = sr0 + it * 32;
        const float* gp = &Qf[((size_t)(b * SL + q0 + r)) * EMB + h * HD + lc * 8];
        float4 f0 = *(const float4*)gp, f1 = *(const float4*)(gp + 4);
        uint4 u = { pk2(f0.x,f0.y), pk2(f0.z,f0.w), pk2(f1.x,f1.y), pk2(f1.z,f1.w) };
        *(uint4*)&sQP[r * 64 + ((lc ^ (r & 7)) * 8)] = u;
    }
    __syncthreads();

    // hoist Q B-frags
    const int qrow = w * 16 + m16;
    bf16x8 bQ[2];
    #pragma unroll
    for (int hh = 0; hh < 2; ++hh)
        bQ[hh] = *(const bf16x8*)&sQP[qrow * 64 + (((hh * 4 + quad) ^ (qrow & 7)) * 8)];
    __syncthreads();   // Q dead; sQP becomes P

    f32x4 O[4] = {};
    f32x4 lacc = {};
    const float CSC = 0.125f * 1.44269504f;
    const short one_bf = (short)0x3F80;
    const bf16x8 ones = { one_bf, one_bf, one_bf, one_bf, one_bf, one_bf, one_bf, one_bf };

    for (int kt = 0; kt < 16; ++kt) {
        const int bf = kt & 1;
        if (kt < 15) {
            const int k0n = (kt + 1) * 64;
            #pragma unroll
            for (int i = 0; i < 2; ++i) {
                int row = w * 16 + i * 8;
                gload_lds16(&Vt[vbase + (size_t)(row + lr) * SL + k0n + (lc ^ lr) * 8],
                            &sVt[bf ^ 1][row * 64]);
                gload_lds16(&Kb[kbase + (size_t)(k0n + row + lr) * HD + (lc ^ lr) * 8],
                            &sK[bf ^ 1][row * 64]);
            }
        }
        unsigned long long mb = Mbt[(size_t)(b * 16 + kt) * SL + q0 + qrow];

        // scores: S^T[64k][16q]
        f32x4 sc[4];
        #pragma unroll
        for (int t = 0; t < 4; ++t) {
            int krow = t * 16 + m16;
            bf16x8 a0 = *(const bf16x8*)&sK[bf][krow * 64 + ((quad ^ (krow & 7)) * 8)];
            bf16x8 a1 = *(const bf16x8*)&sK[bf][krow * 64 + (((4 + quad) ^ (krow & 7)) * 8)];
            f32x4 z = {0.f, 0.f, 0.f, 0.f};
            sc[t] = __builtin_amdgcn_mfma_f32_16x16x32_bf16(a0, bQ[0], z,     0, 0, 0);
            sc[t] = __builtin_amdgcn_mfma_f32_16x16x32_bf16(a1, bQ[1], sc[t], 0, 0, 0);
        }

        // exp2 (fixed shift) + VALU mask words on packed bf16; P write (XOR-chunk)
        {
            unsigned wlo = (unsigned)mb, whi = (unsigned)(mb >> 32);
            #pragma unroll
            for (int t = 0; t < 4; ++t) {
                unsigned word = (t < 2) ? wlo : whi;
                unsigned nib = (word >> ((t & 1) * 16 + quad * 4)) & 0xFu;
                unsigned am0 = ((nib & 1u) ? 0xFFFFu : 0u) | ((nib & 2u) ? 0xFFFF0000u : 0u);
                unsigned am1 = ((nib & 4u) ? 0xFFFFu : 0u) | ((nib & 8u) ? 0xFFFF0000u : 0u);
                uint2 pw;
                pw.x = pk2(exp2_fast(sc[t][0] * CSC), exp2_fast(sc[t][1] * CSC)) & am0;
                pw.y = pk2(exp2_fast(sc[t][2] * CSC), exp2_fast(sc[t][3] * CSC)) & am1;
                // k-chunk c = 2t + (quad>>1), within-chunk offset (quad&1)*4
                int c = 2 * t + (quad >> 1);
                *(uint2*)&sQP[qrow * 64 + ((c ^ (qrow & 7)) * 8 + (quad & 1) * 4)] = pw;
            }
        }
        asm volatile("s_waitcnt lgkmcnt(0)" ::: "memory");   // wave-local P write->read

        bf16x8 bP[2];
        #pragma unroll
        for (int hh = 0; hh < 2; ++hh)
            bP[hh] = *(const bf16x8*)&sQP[qrow * 64 + (((hh * 4 + quad) ^ (qrow & 7)) * 8)];

        // l accumulation: lacc += 1^T P
        lacc = __builtin_amdgcn_mfma_f32_16x16x32_bf16(ones, bP[0], lacc, 0, 0, 0);
        lacc = __builtin_amdgcn_mfma_f32_16x16x32_bf16(ones, bP[1], lacc, 0, 0, 0);

        // PV: O^T[64d][16q] += V^T P
        #pragma unroll
        for (int dt = 0; dt < 4; ++dt) {
            int drow = dt * 16 + m16;
            bf16x8 v0 = *(const bf16x8*)&sVt[bf][drow * 64 + ((quad ^ (drow & 7)) * 8)];
            bf16x8 v1 = *(const bf16x8*)&sVt[bf][drow * 64 + (((4 + quad) ^ (drow & 7)) * 8)];
            O[dt] = __builtin_amdgcn_mfma_f32_16x16x32_bf16(v0, bP[0], O[dt], 0, 0, 0);
            O[dt] = __builtin_amdgcn_mfma_f32_16x16x32_bf16(v1, bP[1], O[dt], 0, 0, 0);
        }

        __syncthreads();   // drains gloads into buf^1 + all waves done with buf
    }

    // epilogue: per-lane l (col q = m16), normalize, store bf16
    {
        float inv = 1.f / lacc[0];
        size_t base = ((size_t)(b * SL + q0 + qrow)) * EMB + h * HD + quad * 4;
        #pragma unroll
        for (int dt = 0; dt < 4; ++dt) {
            uint2 ow = { pk2(O[dt][0] * inv, O[dt][1] * inv),
                         pk2(O[dt][2] * inv, O[dt][3] * inv) };
            *(uint2*)&Oa[base + dt * 16] = ow;
        }
    }
}

// ---------------- Projection: C[4096][1024] = A_bf16 @ W_bf16^T + bias ----------------
// 512 threads (8 waves), 128x128 tile, wave = 64m x 32n, BK=64, dbuf, 1 barrier/it.
__global__ __launch_bounds__(512, 2) void proj_mfma(
    const unsigned short* __restrict__ A, const unsigned short* __restrict__ Wb,
    const float* __restrict__ bias, float* __restrict__ C)
{
    const int n0 = blockIdx.x * 128;
    const int m0 = blockIdx.y * 128;
    const int tid = threadIdx.x;
    const int w = tid >> 6, lane = tid & 63;
    const int m16 = lane & 15, quad = lane >> 4;
    const int lr = lane >> 3, lc = lane & 7;
    const int wm = (w >> 2) * 64, wn = (w & 3) * 32;

    __shared__ __align__(16) unsigned short sA[2][128 * 64];
    __shared__ __align__(16) unsigned short sW[2][128 * 64];

    f32x4 acc[4][2] = {};

    #pragma unroll
    for (int i = 0; i < 2; ++i) {
        int r = w * 16 + i * 8;
        gload_lds16(&A [(size_t)(m0 + r + lr) * EMB + (lc ^ lr) * 8], &sA[0][r * 64]);
        gload_lds16(&Wb[(size_t)(n0 + r + lr) * EMB + (lc ^ lr) * 8], &sW[0][r * 64]);
    }
    __syncthreads();

    for (int it = 0; it < 16; ++it) {
        const int bf = it & 1;
        if (it < 15) {
            int e0 = (it + 1) * 64;
            #pragma unroll
            for (int i = 0; i < 2; ++i) {
                int r = w * 16 + i * 8;
                gload_lds16(&A [(size_t)(m0 + r + lr) * EMB + e0 + (lc ^ lr) * 8], &sA[bf ^ 1][r * 64]);
                gload_lds16(&Wb[(size_t)(n0 + r + lr) * EMB + e0 + (lc ^ lr) * 8], &sW[bf ^ 1][r * 64]);
            }
        }
        #pragma unroll
        for (int hh = 0; hh < 2; ++hh) {
            bf16x8 af[4], bw[2];
            #pragma unroll
            for (int mt = 0; mt < 4; ++mt) {
                int r = wm + mt * 16 + m16;
                af[mt] = *(const bf16x8*)&sA[bf][r * 64 + (((hh * 4 + quad) ^ (r & 7)) * 8)];
            }
            #pragma unroll
            for (int nt = 0; nt < 2; ++nt) {
                int r = wn + nt * 16 + m16;
                bw[nt] = *(const bf16x8*)&sW[bf][r * 64 + (((hh * 4 + quad) ^ (r & 7)) * 8)];
            }
            #pragma unroll
            for (int mt = 0; mt < 4; ++mt)
                #pragma unroll
                for (int nt = 0; nt < 2; ++nt)
                    acc[mt][nt] = __builtin_amdgcn_mfma_f32_16x16x32_bf16(af[mt], bw[nt], acc[mt][nt], 0,0,0);
        }
        __syncthreads();
    }

    #pragma unroll
    for (int nt = 0; nt < 2; ++nt) {
        float bv = bias[n0 + wn + nt * 16 + m16];
        #pragma unroll
        for (int mt = 0; mt < 4; ++mt) {
            size_t row = (size_t)(m0 + wm + mt * 16 + quad * 4);
            #pragma unroll
            for (int rg = 0; rg < 4; ++rg)
                C[(row + rg) * EMB + n0 + wn + nt * 16 + m16] = acc[mt][nt][rg] + bv;
        }
    }
}

extern "C" void kernel_launch(void* const* d_in, const int* in_sizes, int n_in,
                              void* d_out, int out_size, void* d_ws, size_t ws_size,
                              hipStream_t stream) {
    const float* Q    = (const float*)d_in[0];
    const float* K    = (const float*)d_in[1];
    const float* V    = (const float*)d_in[2];
    const int*   mask = (const int*)  d_in[3];
    const float* W    = (const float*)d_in[4];
    const float* bias = (const float*)d_in[5];

    unsigned short* Oa = (unsigned short*)d_ws;                              // 8.39 MB
    unsigned short* Wb = Oa + (size_t)NB * SL * EMB;                         // 2.10 MB
    unsigned long long* Mbt = (unsigned long long*)(Wb + (size_t)EMB * EMB); // 0.52 MB
    unsigned short* Vt = (unsigned short*)(Mbt + (size_t)NB * 16 * SL);      // 8.39 MB
    unsigned short* Kb = Vt + (size_t)NB * NH * HD * SL;                     // 8.39 MB

    prep<<<7168, 256, 0, stream>>>(W, Wb, K, Kb, V, Vt, mask, Mbt);
    attn_mfma<<<1024, 256, 0, stream>>>(Q, Kb, Vt, Mbt, Oa);
    proj_mfma<<<dim3(EMB / 128, (NB * SL) / 128), 512, 0, stream>>>(Oa, Wb, bias, (float*)d_out);
}